// Round 1
// baseline (58531.329 us; speedup 1.0000x reference)
//
#include <hip/hip_runtime.h>
#include <cstdint>
#include <cstddef>

// Problem dims (fixed by setup_inputs)
#define B_   32
#define T_   512
#define D_   1024
#define S_   256
#define M_   10
#define G4   4096   // 4*D
#define K3   3072   // 2*D (x=[inp,ctx]) + D (h)
#define NBLK 256
#define NTHR 256

// out layout: ctx (B,1,D) [32768] | alignment (B,T,S) [4194304] | termination (B,1) [32]
#define AL_OFF   32768
#define TERM_OFF (32768 + (size_t)B_*T_*S_)

// ---------------- grid barrier (custom, two-level, device-scope) ----------------
// bar layout (unsigned): cnt_grp at [32*g], cnt_master at [256], gen_grp at [512+32*g]
__device__ __forceinline__ void gbar(unsigned* bar, unsigned g) {
    __syncthreads();
    if (threadIdx.x == 0) {
        __threadfence();                       // release my writes (device scope)
        const int grp = blockIdx.x & 7;
        unsigned* cnt  = bar + 32*grp;
        unsigned* cntm = bar + 256;
        unsigned* gen  = bar + 512 + 32*grp;
        bool done = false;
        unsigned old = __hip_atomic_fetch_add(cnt, 1u, __ATOMIC_ACQ_REL, __HIP_MEMORY_SCOPE_AGENT);
        if (old == 31u) {
            unsigned old2 = __hip_atomic_fetch_add(cntm, 1u, __ATOMIC_ACQ_REL, __HIP_MEMORY_SCOPE_AGENT);
            if (old2 == 7u) {   // last of last group: reset counters, release everyone
                for (int i = 0; i < 8; ++i)
                    __hip_atomic_store(bar + 32*i, 0u, __ATOMIC_RELAXED, __HIP_MEMORY_SCOPE_AGENT);
                __hip_atomic_store(cntm, 0u, __ATOMIC_RELAXED, __HIP_MEMORY_SCOPE_AGENT);
                for (int i = 0; i < 8; ++i)
                    __hip_atomic_store(bar + 512 + 32*i, g + 1u, __ATOMIC_RELEASE, __HIP_MEMORY_SCOPE_AGENT);
                done = true;
            }
        }
        if (!done) {
            while (__hip_atomic_load(gen, __ATOMIC_RELAXED, __HIP_MEMORY_SCOPE_AGENT) == g)
                __builtin_amdgcn_s_sleep(2);
        }
        __threadfence();                       // acquire side
    }
    __syncthreads();
}

// ---------------- pack: WrecT[k][j] = k<2048 ? W_ih[j][k] : W_hh[j][k-2048] ----------------
__global__ __launch_bounds__(256) void k_pack(const float* __restrict__ Wih,
                                              const float* __restrict__ Whh,
                                              float* __restrict__ WrecT) {
    const int kt = blockIdx.x;   // 0..95
    const int jt = blockIdx.y;   // 0..127
    __shared__ float Tt[32][33];
    const int r = threadIdx.x >> 3;   // 0..31
    const int q = threadIdx.x & 7;    // 0..7
    const int j = jt*32 + r;
    const int k = kt*32 + q*4;
    float4 v;
    if (k < 2048) v = *(const float4*)&Wih[(size_t)j*2048 + k];
    else          v = *(const float4*)&Whh[(size_t)j*1024 + (k - 2048)];
    Tt[r][q*4+0] = v.x; Tt[r][q*4+1] = v.y; Tt[r][q*4+2] = v.z; Tt[r][q*4+3] = v.w;
    __syncthreads();
    float4 o;
    o.x = Tt[q*4+0][r]; o.y = Tt[q*4+1][r]; o.z = Tt[q*4+2][r]; o.w = Tt[q*4+3][r];
    *(float4*)&WrecT[(size_t)(kt*32 + r)*G4 + jt*32 + q*4] = o;
}

// ---------------- bsum + barrier init ----------------
__global__ __launch_bounds__(256) void k_bsum(const float* __restrict__ bih,
                                              const float* __restrict__ bhh,
                                              float* __restrict__ bsum,
                                              unsigned* __restrict__ bar) {
    int i = blockIdx.x*256 + threadIdx.x;
    if (i < G4) bsum[i] = bih[i] + bhh[i];
    if (blockIdx.x == 0)
        for (int j = threadIdx.x; j < 1024; j += 256) bar[j] = 0u;
}

// ---------------- persistent recurrent kernel ----------------
__global__ __launch_bounds__(NTHR, 1) void k_rec(
    const float* __restrict__ inp,   // (B,T,D)
    const float* __restrict__ mem,   // (B,S,D)
    const int*   __restrict__ lens,  // (B,)
    const float* __restrict__ Wg,    // (30,1024)
    const float* __restrict__ bg,    // (30,)
    const float* __restrict__ WrecT, // (3072,4096)
    const float* __restrict__ bsum,  // (4096,)
    float* __restrict__ xh,          // (B,2048): [ctx | h]
    float* __restrict__ cst,         // (B,1024)
    float* __restrict__ ksi,         // (B,16) first 10 used
    float* __restrict__ part,        // (8,B,4096)
    float* __restrict__ wcur,        // (B,256)
    unsigned* __restrict__ bar,
    float* __restrict__ out)
{
    __shared__ __align__(16) float smem[5632];
    const int blk = blockIdx.x;
    const int tid = threadIdx.x;
    unsigned bgen = 0;

    // zero persistent state
    if (blk < B_) {
        for (int i = tid; i < 2*D_; i += NTHR) xh[blk*2*D_ + i] = 0.f;
        for (int i = tid; i < D_; i += NTHR)   cst[blk*D_ + i]  = 0.f;
        if (tid < M_) ksi[blk*16 + tid] = 0.f;
    }
    gbar(bar, bgen); ++bgen;

    for (int t = 0; t < T_; ++t) {
        // ================= P1: gates partial GEMM (all 256 blocks) =================
        // block = (kc 0..7, jb 0..31); computes part[kc][b=0..31][jbase..jbase+128)
        {
            const int kc = blk & 7;
            const int jb = blk >> 3;
            const int jbase = jb * 128;
            const int tx = tid & 31;    // j-group
            const int ty = tid >> 5;    // b-group
            const int sb = tid >> 3;    // staging: b row 0..31
            const int sk = tid & 7;     // staging: k-quad 0..7
            float* Ws = smem;           // [32][132]
            float* Xs = smem + 32*132;  // [32][36]
            float acc[4][4] = {{0.f}};
            float4 xv, wv[4];

            auto loadX = [&](int kbase) {
                if (kbase < D_) xv = *(const float4*)&inp[((size_t)sb*T_ + t)*D_ + kbase + sk*4];
                else            xv = *(const float4*)&xh[sb*2*D_ + (kbase - D_) + sk*4];
            };
            auto loadW = [&](int kbase) {
                #pragma unroll
                for (int r = 0; r < 4; ++r) {
                    int id2 = tid + NTHR*r;
                    int wk = id2 >> 5;
                    int wj = (id2 & 31) << 2;
                    wv[r] = *(const float4*)&WrecT[(size_t)(kbase + wk)*G4 + jbase + wj];
                }
            };

            loadX(kc*384); loadW(kc*384);
            for (int kt2 = 0; kt2 < 12; ++kt2) {
                __syncthreads();
                Xs[(sk*4+0)*36 + sb] = xv.x;
                Xs[(sk*4+1)*36 + sb] = xv.y;
                Xs[(sk*4+2)*36 + sb] = xv.z;
                Xs[(sk*4+3)*36 + sb] = xv.w;
                #pragma unroll
                for (int r = 0; r < 4; ++r) {
                    int id2 = tid + NTHR*r;
                    int wk = id2 >> 5;
                    int wj = (id2 & 31) << 2;
                    *(float4*)&Ws[wk*132 + wj] = wv[r];
                }
                __syncthreads();
                if (kt2 < 11) { loadX(kc*384 + (kt2+1)*32); loadW(kc*384 + (kt2+1)*32); }
                #pragma unroll
                for (int kk = 0; kk < 32; ++kk) {
                    float4 wr = *(const float4*)&Ws[kk*132 + (tx<<2)];
                    float4 xr = *(const float4*)&Xs[kk*36  + (ty<<2)];
                    acc[0][0] += xr.x*wr.x; acc[0][1] += xr.x*wr.y; acc[0][2] += xr.x*wr.z; acc[0][3] += xr.x*wr.w;
                    acc[1][0] += xr.y*wr.x; acc[1][1] += xr.y*wr.y; acc[1][2] += xr.y*wr.z; acc[1][3] += xr.y*wr.w;
                    acc[2][0] += xr.z*wr.x; acc[2][1] += xr.z*wr.y; acc[2][2] += xr.z*wr.z; acc[2][3] += xr.z*wr.w;
                    acc[3][0] += xr.w*wr.x; acc[3][1] += xr.w*wr.y; acc[3][2] += xr.w*wr.z; acc[3][3] += xr.w*wr.w;
                }
            }
            #pragma unroll
            for (int i = 0; i < 4; ++i) {
                int b = (ty<<2) + i;
                *(float4*)&part[(size_t)(kc*B_ + b)*G4 + jbase + (tx<<2)] =
                    make_float4(acc[i][0], acc[i][1], acc[i][2], acc[i][3]);
            }
        }
        gbar(bar, bgen); ++bgen;

        // ================= P2: cell + attention head (blocks 0..31) =================
        if (blk < B_) {
            const int b = blk;
            float* gl = smem;           // 4096 gates
            float* hl = smem + 4096;    // 1024 h
            float* sm = smem + 5120;    // scratch
            for (int j = tid; j < G4; j += NTHR) {
                float s = bsum[j];
                #pragma unroll
                for (int kc = 0; kc < 8; ++kc) s += part[(size_t)(kc*B_ + b)*G4 + j];
                gl[j] = s;
            }
            __syncthreads();
            for (int d = tid; d < D_; d += NTHR) {
                float ig = 1.f/(1.f + expf(-gl[d]));
                float fg = 1.f/(1.f + expf(-gl[D_ + d]));
                float gg = tanhf(gl[2*D_ + d]);
                float og = 1.f/(1.f + expf(-gl[3*D_ + d]));
                float cn = fg*cst[b*D_ + d] + ig*gg;
                float hn = og*tanhf(cn);
                cst[b*D_ + d] = cn;
                hl[d] = hn;
                xh[b*2*D_ + D_ + d] = hn;   // h half
            }
            __syncthreads();
            {   // phi[m] = h . Wg[m] + bg[m], m<30; 8 lanes per m
                int m = tid >> 3, l = tid & 7;
                if (m < 30) {
                    float a = 0.f;
                    for (int d0 = l; d0 < D_; d0 += 8) a += hl[d0]*Wg[m*D_ + d0];
                    a += __shfl_down(a, 4, 8);
                    a += __shfl_down(a, 2, 8);
                    a += __shfl_down(a, 1, 8);
                    if (l == 0) sm[m] = a + bg[m];
                }
            }
            __syncthreads();
            if (tid < M_) {
                int mm = tid;
                sm[32+mm] = expf(sm[20+mm]);   // raw alpha (softmax scale cancels in w)
                float kn = fminf(ksi[b*16+mm] + expf(sm[mm]), (float)(S_-1));
                ksi[b*16+mm] = kn;
                sm[48+mm] = kn;
                sm[64+mm] = expf(sm[10+mm]);   // beta
            }
            if (tid == 0) {
                float se = 0.f;
                #pragma unroll
                for (int mm = 0; mm < M_; ++mm) se += expf(sm[20+mm]);
                sm[88] = se;                   // softmax denom (needed for termination only)
            }
            __syncthreads();
            {
                int s = tid;   // 0..255 = S
                float t1 = 0.f, t2 = 0.f;
                #pragma unroll
                for (int mm = 0; mm < M_; ++mm) {
                    float a = sm[32+mm], kk = sm[48+mm], be = sm[64+mm];
                    float xr = ((float)s + 0.5f - kk)/be;
                    float xl = ((float)s - 0.5f - kk)/be;
                    t1 += a/(1.f + expf(-xr));
                    t2 += a/(1.f + expf(-xl));
                }
                float wraw = t1 - t2;
                float v = wraw;
                v += __shfl_down(v, 32); v += __shfl_down(v, 16); v += __shfl_down(v, 8);
                v += __shfl_down(v, 4);  v += __shfl_down(v, 2);  v += __shfl_down(v, 1);
                if ((tid & 63) == 0) sm[96 + (tid >> 6)] = v;
                __syncthreads();
                float wsum = sm[96] + sm[97] + sm[98] + sm[99];
                float w = wraw / wsum;
                wcur[b*S_ + s] = w;
                out[AL_OFF + ((size_t)b*T_ + t)*S_ + s] = w;
                if (t == T_-1) {
                    int idx = lens[b] - 1;
                    idx = idx < 0 ? 0 : (idx > S_-1 ? S_-1 : idx);
                    if (s == idx) out[TERM_OFF + b] = 1.f - t1/sm[88];
                }
            }
        }
        gbar(bar, bgen); ++bgen;

        // ================= P3: ctx = w . memory (all 256 blocks) =================
        {
            const int b  = blk & 31;
            const int dc = blk >> 5;   // 0..7, 128 d each
            float* wl  = smem;         // [256]
            float* red = smem + 256;   // [128]
            wl[tid] = wcur[b*S_ + tid];
            __syncthreads();
            const int dd = tid & 127;
            const int sh = tid >> 7;   // s-half
            const int d  = dc*128 + dd;
            const float* mp = mem + ((size_t)b*S_ + sh*128)*D_ + d;
            float acc = 0.f;
            #pragma unroll 8
            for (int s2 = 0; s2 < 128; ++s2) acc += wl[sh*128 + s2] * mp[(size_t)s2*D_];
            if (sh) red[dd] = acc;
            __syncthreads();
            if (!sh) {
                float v = acc + red[dd];
                xh[b*2*D_ + d] = v;                     // ctx half
                if (t == T_-1) out[(size_t)b*D_ + d] = v;
            }
        }
        gbar(bar, bgen); ++bgen;
    }
}

// ---------------- host ----------------
extern "C" void kernel_launch(void* const* d_in, const int* in_sizes, int n_in,
                              void* d_out, int out_size, void* d_ws, size_t ws_size,
                              hipStream_t stream) {
    const float* inp  = (const float*)d_in[0];
    const float* mem  = (const float*)d_in[1];
    const int*   lens = (const int*)  d_in[2];
    const float* Wih  = (const float*)d_in[3];
    const float* Whh  = (const float*)d_in[4];
    const float* bih  = (const float*)d_in[5];
    const float* bhh  = (const float*)d_in[6];
    const float* Wg   = (const float*)d_in[7];
    const float* bg   = (const float*)d_in[8];
    float* out = (float*)d_out;

    float* WrecT = (float*)d_ws;                    // 3072*4096
    float* part  = WrecT + (size_t)K3*G4;           // 8*32*4096
    float* xh    = part + (size_t)8*B_*G4;          // 32*2048
    float* cst   = xh + B_*2*D_;                    // 32*1024
    float* ksi   = cst + B_*D_;                     // 32*16
    float* wcur  = ksi + B_*16;                     // 32*256
    float* bsum  = wcur + B_*S_;                    // 4096
    unsigned* bar = (unsigned*)(bsum + G4);         // 1024 u32
    size_t need = (size_t)((char*)(bar + 1024) - (char*)d_ws);
    if (ws_size < need) return;  // learn ws_size from a clean "incorrect" rather than corrupting

    hipLaunchKernelGGL(k_pack, dim3(96,128), dim3(256), 0, stream, Wih, Whh, WrecT);
    hipLaunchKernelGGL(k_bsum, dim3(16), dim3(256), 0, stream, bih, bhh, bsum, bar);

    void* args[] = { (void*)&inp, (void*)&mem, (void*)&lens, (void*)&Wg, (void*)&bg,
                     (void*)&WrecT, (void*)&bsum, (void*)&xh, (void*)&cst, (void*)&ksi,
                     (void*)&part, (void*)&wcur, (void*)&bar, (void*)&out };
    hipError_t e = hipLaunchCooperativeKernel((void*)k_rec, dim3(NBLK), dim3(NTHR),
                                              args, 0, stream);
    if (e != hipSuccess) {
        // 256 blocks x 256 thr (1 block/CU, 22.5KB LDS) is trivially co-resident;
        // barrier is custom (no CG dependency), so a plain launch is also correct.
        hipLaunchKernelGGL(k_rec, dim3(NBLK), dim3(NTHR), 0, stream,
                           inp, mem, lens, Wg, bg, WrecT, bsum, xh, cst, ksi,
                           part, wcur, bar, out);
    }
}

// Round 9
// 56550.757 us; speedup vs baseline: 1.0350x; 1.0350x over previous
//
#include <hip/hip_runtime.h>
#include <cstdint>
#include <cstddef>

// Problem dims (fixed by setup_inputs)
#define B_   32
#define T_   512
#define D_   1024
#define S_   256
#define M_   10
#define G4   4096   // 4*D
#define K3   3072   // 2*D (x=[inp,ctx]) + D (h)
#define NBLK 256
#define NTHR 256

// out layout: ctx (B,1,D) [32768] | alignment (B,T,S) [4194304] | termination (B,1) [32]
#define AL_OFF   32768
#define TERM_OFF (32768 + (size_t)B_*T_*S_)

// Xs: [32 b][row-stride 400]; col = k4*4 + 4*((k4/24)&3) skew so the 8 tk read
// groups hit 8 distinct bank quads; stride 400 keeps float4 (16B) alignment.
#define XS_STRIDE 400

// ---------------- grid barrier (custom, two-level, device-scope) ----------------
__device__ __forceinline__ void gbar(unsigned* bar, unsigned g) {
    __syncthreads();
    if (threadIdx.x == 0) {
        __threadfence();
        const int grp = blockIdx.x & 7;
        unsigned* cnt  = bar + 32*grp;
        unsigned* cntm = bar + 256;
        unsigned* gen  = bar + 512 + 32*grp;
        bool done = false;
        unsigned old = __hip_atomic_fetch_add(cnt, 1u, __ATOMIC_ACQ_REL, __HIP_MEMORY_SCOPE_AGENT);
        if (old == 31u) {
            unsigned old2 = __hip_atomic_fetch_add(cntm, 1u, __ATOMIC_ACQ_REL, __HIP_MEMORY_SCOPE_AGENT);
            if (old2 == 7u) {
                for (int i = 0; i < 8; ++i)
                    __hip_atomic_store(bar + 32*i, 0u, __ATOMIC_RELAXED, __HIP_MEMORY_SCOPE_AGENT);
                __hip_atomic_store(cntm, 0u, __ATOMIC_RELAXED, __HIP_MEMORY_SCOPE_AGENT);
                for (int i = 0; i < 8; ++i)
                    __hip_atomic_store(bar + 512 + 32*i, g + 1u, __ATOMIC_RELEASE, __HIP_MEMORY_SCOPE_AGENT);
                done = true;
            }
        }
        if (!done) {
            while (__hip_atomic_load(gen, __ATOMIC_RELAXED, __HIP_MEMORY_SCOPE_AGENT) == g)
                __builtin_amdgcn_s_sleep(2);
        }
        __threadfence();
    }
    __syncthreads();
}

// ---------------- pack: WrecT[k][j] = k<2048 ? W_ih[j][k] : W_hh[j][k-2048] ----------------
__global__ __launch_bounds__(256) void k_pack(const float* __restrict__ Wih,
                                              const float* __restrict__ Whh,
                                              float* __restrict__ WrecT) {
    const int kt = blockIdx.x;   // 0..95
    const int jt = blockIdx.y;   // 0..127
    __shared__ float Tt[32][33];
    const int r = threadIdx.x >> 3;   // 0..31
    const int q = threadIdx.x & 7;    // 0..7
    const int j = jt*32 + r;
    const int k = kt*32 + q*4;
    float4 v;
    if (k < 2048) v = *(const float4*)&Wih[(size_t)j*2048 + k];
    else          v = *(const float4*)&Whh[(size_t)j*1024 + (k - 2048)];
    Tt[r][q*4+0] = v.x; Tt[r][q*4+1] = v.y; Tt[r][q*4+2] = v.z; Tt[r][q*4+3] = v.w;
    __syncthreads();
    float4 o;
    o.x = Tt[q*4+0][r]; o.y = Tt[q*4+1][r]; o.z = Tt[q*4+2][r]; o.w = Tt[q*4+3][r];
    *(float4*)&WrecT[(size_t)(kt*32 + r)*G4 + jt*32 + q*4] = o;
}

// ---------------- bsum + barrier init ----------------
__global__ __launch_bounds__(256) void k_bsum(const float* __restrict__ bih,
                                              const float* __restrict__ bhh,
                                              float* __restrict__ bsum,
                                              unsigned* __restrict__ bar) {
    int i = blockIdx.x*256 + threadIdx.x;
    if (i < G4) bsum[i] = bih[i] + bhh[i];
    if (blockIdx.x == 0)
        for (int j = threadIdx.x; j < 1024; j += 256) bar[j] = 0u;
}

// ---------------- persistent recurrent kernel ----------------
// Block (kc=blk&7, jb=blk>>3) for P1; (b2=blk&31, dc=blk>>5) for P2/P3.
// Thread (tk=tid&7, tj=tid>>3): owns W[48k x 4j] in registers (192 VGPR).
__global__ __launch_bounds__(NTHR, 1) void k_rec(
    const float* __restrict__ inp,   // (B,T,D)
    const float* __restrict__ mem,   // (B,S,D)
    const int*   __restrict__ lens,  // (B,)
    const float* __restrict__ Wg,    // (30,1024)
    const float* __restrict__ bg,    // (30,)
    const float* __restrict__ WrecT, // (3072,4096)
    const float* __restrict__ bsum,  // (4096,)
    float* __restrict__ xh,          // (B,2048): [ctx | h]
    float* __restrict__ part,        // (8,B,4096)
    unsigned* __restrict__ bar,
    float* __restrict__ out)
{
    __shared__ __align__(16) float Xs[B_*XS_STRIDE];   // 51.2 KB
    __shared__ __align__(16) float hl[D_];             // 4 KB
    __shared__ float wl[S_];
    __shared__ float sm[128];
    __shared__ float red[128];
    __shared__ float ksi_l[16];

    const int blk = blockIdx.x;
    const int tid = threadIdx.x;
    const int kc = blk & 7;
    const int jb = blk >> 3;
    const int tk = tid & 7;
    const int tj = tid >> 3;
    const int j0 = jb*128 + tj*4;
    const int b2 = blk & 31;
    const int dc = blk >> 5;
    unsigned bgen = 0;

    // ---- persistent W in registers: Wreg[kk*4+jj], kk 0..47 ----
    float Wreg[192];
    {
        const int kb = kc*384 + tk*48;
        #pragma unroll
        for (int kk = 0; kk < 48; ++kk) {
            float4 w4 = *(const float4*)&WrecT[(size_t)(kb + kk)*G4 + j0];
            Wreg[kk*4+0] = w4.x; Wreg[kk*4+1] = w4.y;
            Wreg[kk*4+2] = w4.z; Wreg[kk*4+3] = w4.w;
        }
    }
    // bias preload (constant across steps)
    float4 bs4[4];
    #pragma unroll
    for (int g = 0; g < 4; ++g) bs4[g] = *(const float4*)&bsum[g*D_ + tid*4];

    float creg[4] = {0.f, 0.f, 0.f, 0.f};   // persistent c-state (this block's b2, d=tid*4..+4)

    if (blk < B_) for (int i = tid; i < 2*D_; i += NTHR) xh[blk*2*D_ + i] = 0.f;
    if (tid < 16) ksi_l[tid] = 0.f;
    gbar(bar, bgen); ++bgen;

    const int colb = tk*48 + 4*((tk>>1)&3);   // skewed read base (matches write-side skew)

    for (int t = 0; t < T_; ++t) {
        // ================= P1 stage: x[b][kc-slice] -> LDS =================
        #pragma unroll
        for (int it = 0; it < 12; ++it) {
            int fid = it*NTHR + tid;          // 0..3071
            int b   = fid / 96;
            int k4  = fid - b*96;
            int k   = kc*384 + k4*4;
            float4 v;
            if (k < D_) v = *(const float4*)&inp[((size_t)b*T_ + t)*D_ + k];
            else        v = *(const float4*)&xh[b*2*D_ + (k - D_)];
            int col = k4*4 + 4*((k4/24)&3);   // same skew as read side
            *(float4*)&Xs[b*XS_STRIDE + col] = v;
        }
        __syncthreads();
        // ================= P1 compute: per-thread 4j x 48k, 8 b-quads =================
        for (int bq = 0; bq < 8; ++bq) {
            float acc[4][4] = {{0.f,0.f,0.f,0.f},{0.f,0.f,0.f,0.f},
                               {0.f,0.f,0.f,0.f},{0.f,0.f,0.f,0.f}};
            const float* x0 = &Xs[(bq*4+0)*XS_STRIDE + colb];
            const float* x1 = &Xs[(bq*4+1)*XS_STRIDE + colb];
            const float* x2 = &Xs[(bq*4+2)*XS_STRIDE + colb];
            const float* x3 = &Xs[(bq*4+3)*XS_STRIDE + colb];
            #pragma unroll
            for (int kq = 0; kq < 12; ++kq) {
                float4 f0 = *(const float4*)(x0 + kq*4);
                float4 f1 = *(const float4*)(x1 + kq*4);
                float4 f2 = *(const float4*)(x2 + kq*4);
                float4 f3 = *(const float4*)(x3 + kq*4);
                const float* W0 = &Wreg[kq*16];
                #pragma unroll
                for (int jj = 0; jj < 4; ++jj) {
                    float w = W0[jj];
                    acc[0][jj] += f0.x*w; acc[1][jj] += f1.x*w;
                    acc[2][jj] += f2.x*w; acc[3][jj] += f3.x*w;
                }
                #pragma unroll
                for (int jj = 0; jj < 4; ++jj) {
                    float w = W0[4+jj];
                    acc[0][jj] += f0.y*w; acc[1][jj] += f1.y*w;
                    acc[2][jj] += f2.y*w; acc[3][jj] += f3.y*w;
                }
                #pragma unroll
                for (int jj = 0; jj < 4; ++jj) {
                    float w = W0[8+jj];
                    acc[0][jj] += f0.z*w; acc[1][jj] += f1.z*w;
                    acc[2][jj] += f2.z*w; acc[3][jj] += f3.z*w;
                }
                #pragma unroll
                for (int jj = 0; jj < 4; ++jj) {
                    float w = W0[12+jj];
                    acc[0][jj] += f0.w*w; acc[1][jj] += f1.w*w;
                    acc[2][jj] += f2.w*w; acc[3][jj] += f3.w*w;
                }
            }
            // reduce over the 8 tk groups (lanes xor 1,2,4)
            #pragma unroll
            for (int i = 0; i < 4; ++i) {
                #pragma unroll
                for (int jj = 0; jj < 4; ++jj) {
                    float v = acc[i][jj];
                    v += __shfl_xor(v, 1);
                    v += __shfl_xor(v, 2);
                    v += __shfl_xor(v, 4);
                    acc[i][jj] = v;
                }
            }
            if (tk == 0) {
                #pragma unroll
                for (int i = 0; i < 4; ++i) {
                    int b = bq*4 + i;
                    *(float4*)&part[(size_t)(kc*B_ + b)*G4 + j0] =
                        make_float4(acc[i][0], acc[i][1], acc[i][2], acc[i][3]);
                }
            }
        }
        gbar(bar, bgen); ++bgen;

        // ================= P2 (replicated on ALL blocks): cell + GMM head for b2 =================
        {
            const int d4 = tid*4;
            float hv[4];
            {
                float ga[4][4];
                #pragma unroll
                for (int g = 0; g < 4; ++g) {
                    float4 s = bs4[g];
                    #pragma unroll
                    for (int kc2 = 0; kc2 < 8; ++kc2) {
                        float4 p = *(const float4*)&part[(size_t)(kc2*B_ + b2)*G4 + g*D_ + d4];
                        s.x += p.x; s.y += p.y; s.z += p.z; s.w += p.w;
                    }
                    ga[g][0] = s.x; ga[g][1] = s.y; ga[g][2] = s.z; ga[g][3] = s.w;
                }
                #pragma unroll
                for (int i = 0; i < 4; ++i) {
                    float ig = 1.f/(1.f + expf(-ga[0][i]));
                    float fg = 1.f/(1.f + expf(-ga[1][i]));
                    float gg = tanhf(ga[2][i]);
                    float og = 1.f/(1.f + expf(-ga[3][i]));
                    float cn = fg*creg[i] + ig*gg;
                    creg[i] = cn;
                    hv[i] = og*tanhf(cn);
                }
            }
            *(float4*)&hl[d4] = make_float4(hv[0], hv[1], hv[2], hv[3]);
            if (blk < B_) *(float4*)&xh[b2*2*D_ + D_ + d4] = make_float4(hv[0], hv[1], hv[2], hv[3]);
        }
        __syncthreads();
        {   // phi[m] = h . Wg[m] + bg[m], 8 lanes per m
            int m = tid >> 3, l = tid & 7;
            if (m < 30) {
                float a = 0.f;
                const float* wgp = &Wg[m*D_];
                for (int d0 = l; d0 < D_; d0 += 8) a += hl[d0]*wgp[d0];
                a += __shfl_down(a, 4, 8);
                a += __shfl_down(a, 2, 8);
                a += __shfl_down(a, 1, 8);
                if (l == 0) sm[m] = a + bg[m];
            }
        }
        __syncthreads();
        if (tid < M_) {
            sm[32+tid] = expf(sm[20+tid]);                               // raw alpha
            float kn = fminf(ksi_l[tid] + expf(sm[tid]), (float)(S_-1)); // ksi (per-block copy)
            ksi_l[tid] = kn;
            sm[48+tid] = kn;
            sm[64+tid] = expf(sm[10+tid]);                               // beta
        }
        if (tid == 0) {
            float se = 0.f;
            #pragma unroll
            for (int mm = 0; mm < M_; ++mm) se += expf(sm[20+mm]);
            sm[88] = se;   // softmax denom (termination only)
        }
        __syncthreads();
        {
            int s = tid;
            float t1 = 0.f, t2 = 0.f;
            #pragma unroll
            for (int mm = 0; mm < M_; ++mm) {
                float a = sm[32+mm], kk2 = sm[48+mm], be = sm[64+mm];
                float xr = ((float)s + 0.5f - kk2)/be;
                float xl = ((float)s - 0.5f - kk2)/be;
                t1 += a/(1.f + expf(-xr));
                t2 += a/(1.f + expf(-xl));
            }
            float wraw = t1 - t2;
            float v = wraw;
            v += __shfl_down(v, 32); v += __shfl_down(v, 16); v += __shfl_down(v, 8);
            v += __shfl_down(v, 4);  v += __shfl_down(v, 2);  v += __shfl_down(v, 1);
            if ((tid & 63) == 0) sm[96 + (tid >> 6)] = v;
            __syncthreads();
            float wsum = sm[96] + sm[97] + sm[98] + sm[99];
            float w = wraw / wsum;
            wl[s] = w;
            if (blk < B_) {                       // dc==0 replica owns outputs
                out[AL_OFF + ((size_t)b2*T_ + t)*S_ + s] = w;
                if (t == T_-1) {
                    int idx = lens[b2] - 1;
                    idx = idx < 0 ? 0 : (idx > S_-1 ? S_-1 : idx);
                    if (s == idx) out[TERM_OFF + b2] = 1.f - t1/sm[88];
                }
            }
        }
        __syncthreads();
        // ================= P3 (fused, no barrier): ctx = w . memory =================
        {
            const int dd = tid & 127;
            const int sh = tid >> 7;
            const int d  = dc*128 + dd;
            const float* mp = mem + ((size_t)b2*S_ + sh*128)*D_ + d;
            float a3 = 0.f;
            #pragma unroll 8
            for (int s2 = 0; s2 < 128; ++s2) a3 += wl[sh*128 + s2]*mp[(size_t)s2*D_];
            if (sh) red[dd] = a3;
            __syncthreads();
            if (!sh) {
                float v = a3 + red[dd];
                xh[b2*2*D_ + d] = v;
                if (t == T_-1) out[(size_t)b2*D_ + d] = v;
            }
        }
        gbar(bar, bgen); ++bgen;
    }
}

// ---------------- host ----------------
extern "C" void kernel_launch(void* const* d_in, const int* in_sizes, int n_in,
                              void* d_out, int out_size, void* d_ws, size_t ws_size,
                              hipStream_t stream) {
    const float* inp  = (const float*)d_in[0];
    const float* mem  = (const float*)d_in[1];
    const int*   lens = (const int*)  d_in[2];
    const float* Wih  = (const float*)d_in[3];
    const float* Whh  = (const float*)d_in[4];
    const float* bih  = (const float*)d_in[5];
    const float* bhh  = (const float*)d_in[6];
    const float* Wg   = (const float*)d_in[7];
    const float* bg   = (const float*)d_in[8];
    float* out = (float*)d_out;

    float* WrecT = (float*)d_ws;                    // 3072*4096
    float* part  = WrecT + (size_t)K3*G4;           // 8*32*4096
    float* xh    = part + (size_t)8*B_*G4;          // 32*2048
    float* bsum  = xh + (size_t)B_*2*D_;            // 4096
    unsigned* bar = (unsigned*)(bsum + G4);         // 1024 u32
    size_t need = (size_t)((char*)(bar + 1024) - (char*)d_ws);
    if (ws_size < need) return;

    hipLaunchKernelGGL(k_pack, dim3(96,128), dim3(256), 0, stream, Wih, Whh, WrecT);
    hipLaunchKernelGGL(k_bsum, dim3(16), dim3(256), 0, stream, bih, bhh, bsum, bar);

    void* args[] = { (void*)&inp, (void*)&mem, (void*)&lens, (void*)&Wg, (void*)&bg,
                     (void*)&WrecT, (void*)&bsum, (void*)&xh,
                     (void*)&part, (void*)&bar, (void*)&out };
    hipError_t e = hipLaunchCooperativeKernel((void*)k_rec, dim3(NBLK), dim3(NTHR),
                                              args, 0, stream);
    if (e != hipSuccess) {
        // Unconditional plain-launch fallback (round-1 proven path):
        // __launch_bounds__(256,1) + 57.4KB LDS guarantees >=1 block/CU, and
        // grid == 256 == #CUs, so all blocks are co-resident and the custom
        // gbar cannot deadlock. (Round 8's occupancy-query guard appears to
        // have declined to launch anything -> out stayed zero -> absmax 2.27.)
        hipLaunchKernelGGL(k_rec, dim3(NBLK), dim3(NTHR), 0, stream,
                           inp, mem, lens, Wg, bg, WrecT, bsum, xh,
                           part, bar, out);
    }
}